// Round 2
// baseline (593.238 us; speedup 1.0000x reference)
//
#include <hip/hip_runtime.h>
#include <stdint.h>

// ---------------------------------------------------------------------------
// PTBlock fused implementation (B=8, Cin=64, C=128, N=4096, k=16, HID=512)
// Pipeline: P1(weight products) -> P2(pack frag tables + pp) -> A(h=Win x + LN1 -> hn)
//   -> GEMM qkv (hn @ [Wak|Wv|Waq]^T, kv interleaved) -> KNN -> ATTN -> D1(h+y, LN2)
//   -> F1 (FFN up, relu) -> F2 (FFN down + residual add into d_out)
// R2 change: k_knn distance ordering made exact vs true distances:
//   fp32 difference-form pre-filter (loose margin) + f64 exact key
//   (products of fp32 are exact in f64; key = f64bits & ~0xFFF | index).
// ---------------------------------------------------------------------------

typedef __attribute__((ext_vector_type(8))) short s8;
typedef __attribute__((ext_vector_type(4))) float f4;

#define MFMA16(a,b,c) __builtin_amdgcn_mfma_f32_16x16x32_bf16(a,b,c,0,0,0)

__device__ __forceinline__ float bf2f(unsigned short u){
  unsigned x = ((unsigned)u) << 16; return __builtin_bit_cast(float, x);
}
__device__ __forceinline__ unsigned short f2bf(float f){
  unsigned x = __builtin_bit_cast(unsigned, f);
  x = x + 0x7FFFu + ((x >> 16) & 1u);
  return (unsigned short)(x >> 16);
}

// ---------------- sorting-network helpers (u64 keys) -----------------------
__device__ __forceinline__ void ce64(unsigned long long &a, unsigned long long &b){
  unsigned long long x = a, y = b;
  bool c = x < y;
  a = c ? x : y;
  b = c ? y : x;
}
// Batcher odd-even mergesort, n=16 (63 CE)
__device__ __forceinline__ void sort16(unsigned long long v[16]){
  #pragma unroll
  for (int p = 1; p < 16; p <<= 1){
    #pragma unroll
    for (int k = p; k >= 1; k >>= 1){
      #pragma unroll
      for (int j = k % p; j + k < 16; j += 2*k){
        #pragma unroll
        for (int i = 0; i < k; ++i){
          if (i + j + k < 16){
            if (((i+j) / (2*p)) == ((i+j+k) / (2*p))) ce64(v[i+j], v[i+j+k]);
          }
        }
      }
    }
  }
}
// sort a bitonic 16-sequence ascending
__device__ __forceinline__ void bitonic16(unsigned long long v[16]){
  #pragma unroll
  for (int k = 8; k >= 1; k >>= 1){
    #pragma unroll
    for (int i = 0; i < 16; ++i){
      if ((i & k) == 0) ce64(v[i], v[i | k]);
    }
  }
}
// top (asc) x w (asc) -> top = sorted 16 smallest of the 32
__device__ __forceinline__ void merge16(unsigned long long top[16], const unsigned long long w[16]){
  unsigned long long t[16];
  #pragma unroll
  for (int i = 0; i < 16; ++i){
    unsigned long long a = top[i], b = w[15 - i];
    t[i] = a < b ? a : b;
  }
  bitonic16(t);
  #pragma unroll
  for (int i = 0; i < 16; ++i) top[i] = t[i];
}
__device__ __forceinline__ void drain16(unsigned long long* br, int &cnt,
                                        unsigned long long top[16], unsigned long long &thr){
  unsigned long long v[16];
  #pragma unroll
  for (int j = 0; j < 16; ++j){
    unsigned long long t = br[j];
    v[j] = (j < cnt) ? t : ~0ull;
  }
  cnt = 0;
  sort16(v);
  merge16(top, v);
  thr = top[15];
}
// loose f32 upper bound for the d2 encoded in thr (for the fp32 pre-filter)
__device__ __forceinline__ float thr2f(unsigned long long thr){
  if (thr == ~0ull) return __builtin_inff();
  double dt = __builtin_bit_cast(double, (unsigned long long)(thr | 0xFFFull));
  float f = (float)dt;
  return f + fmaxf(f * 2e-6f, 2e-7f);
}

// ---------------- P1: Wak = Wa@Wk, Waq = Wa@Wq, Wda = Wa@Wd2 ---------------
__global__ __launch_bounds__(128) void k_p1(const float* __restrict__ W_a,
    const float* __restrict__ W_k, const float* __restrict__ W_q, const float* __restrict__ W_d2,
    float* __restrict__ tk, float* __restrict__ tq, float* __restrict__ td){
  int which = blockIdx.x >> 7, row = blockIdx.x & 127, c = threadIdx.x;
  const float* X = (which == 0) ? W_k : ((which == 1) ? W_q : W_d2);
  float* O = (which == 0) ? tk : ((which == 1) ? tq : td);
  float acc = 0.f;
  #pragma unroll 8
  for (int i = 0; i < 128; ++i) acc += W_a[row*128 + i] * X[i*128 + c];
  O[row*128 + c] = acc;
}

// ---------------- P2: pack fragment tables, pp, ball -----------------------
// frag index: entry(((tg*S + s)*64 + l)*8 + j) = M[16*tg + (l&15)][32*s + 8*(l>>4) + j]
__global__ __launch_bounds__(256) void k_pack(
    const float* __restrict__ p, const float* __restrict__ W_v,
    const float* __restrict__ W_d1, const float* __restrict__ b_d1,
    const float* __restrict__ W_in, const float* __restrict__ W_f1, const float* __restrict__ W_f2,
    const float* __restrict__ W_a, const float* __restrict__ b_a, const float* __restrict__ b_d2,
    const float* __restrict__ W_d2,
    const float* __restrict__ tk, const float* __restrict__ tq, const float* __restrict__ td,
    float4* __restrict__ pp, unsigned short* __restrict__ wcatf, unsigned short* __restrict__ wf1f,
    unsigned short* __restrict__ wf2f, unsigned short* __restrict__ wd2f,
    unsigned short* __restrict__ wdaf, unsigned short* __restrict__ w1f,
    unsigned short* __restrict__ winf, float* __restrict__ ball){
  int id0 = blockIdx.x * blockDim.x + threadIdx.x;
  int stride = gridDim.x * blockDim.x;
  // pp[b][m] = (px,py,pz,|p|^2)
  for (int i = id0; i < 32768; i += stride){
    int b = i >> 12, m = i & 4095;
    float xx = p[(b*3 + 0)*4096 + m];
    float yy = p[(b*3 + 1)*4096 + m];
    float zz = p[(b*3 + 2)*4096 + m];
    pp[i] = float4{xx, yy, zz, xx*xx + yy*yy + zz*zz};
  }
  // Wcatf: rows 0-127 Wak, 128-255 W_v, 256-383 Waq ; K=128 (S=4)
  for (int i = id0; i < 49152; i += stride){
    int tg = i >> 11, s = (i >> 9) & 3, l = (i >> 3) & 63, j = i & 7;
    int row = tg*16 + (l & 15), k = s*32 + (l >> 4)*8 + j;
    float v;
    if (row < 128) v = tk[row*128 + k];
    else if (row < 256) v = W_v[(row - 128)*128 + k];
    else v = tq[(row - 256)*128 + k];
    wcatf[i] = f2bf(v);
  }
  // Wf1f: 512 rows, K=128 (S=4)
  for (int i = id0; i < 65536; i += stride){
    int tg = i >> 11, s = (i >> 9) & 3, l = (i >> 3) & 63, j = i & 7;
    int row = tg*16 + (l & 15), k = s*32 + (l >> 4)*8 + j;
    wf1f[i] = f2bf(W_f1[row*128 + k]);
  }
  // Wf2f: 128 rows, K=512 (S=16)  (used as A-table in F2)
  for (int i = id0; i < 65536; i += stride){
    int mt = i >> 13, s = (i >> 9) & 15, l = (i >> 3) & 63, j = i & 7;
    int row = mt*16 + (l & 15), k = s*32 + (l >> 4)*8 + j;
    wf2f[i] = f2bf(W_f2[row*512 + k]);
  }
  // Wd2f: 128 rows K=128
  for (int i = id0; i < 16384; i += stride){
    int tg = i >> 11, s = (i >> 9) & 3, l = (i >> 3) & 63, j = i & 7;
    int row = tg*16 + (l & 15), k = s*32 + (l >> 4)*8 + j;
    wd2f[i] = f2bf(W_d2[row*128 + k]);
  }
  // Wdaf from Wda=Wa@Wd2
  for (int i = id0; i < 16384; i += stride){
    int tg = i >> 11, s = (i >> 9) & 3, l = (i >> 3) & 63, j = i & 7;
    int row = tg*16 + (l & 15), k = s*32 + (l >> 4)*8 + j;
    wdaf[i] = f2bf(td[row*128 + k]);
  }
  // W1f: B-frag of W1aug (rows=c, K=4 padded into one 32-step)
  for (int i = id0; i < 4096; i += stride){
    int tg = i >> 9, l = (i >> 3) & 63, j = i & 7;
    int c = tg*16 + (l & 15);
    float v = 0.f;
    if (l < 16 && j < 4) v = (j < 3) ? W_d1[c*3 + j] : b_d1[c];
    w1f[i] = f2bf(v);
  }
  // Winf: 128 rows K=64 (S=2)
  for (int i = id0; i < 8192; i += stride){
    int tg = i >> 10, s = (i >> 9) & 1, l = (i >> 3) & 63, j = i & 7;
    int row = tg*16 + (l & 15), k = s*32 + (l >> 4)*8 + j;
    winf[i] = f2bf(W_in[row*64 + k]);
  }
  // ball[o] = b_a[o] + sum_c W_a[o][c]*b_d2[c]
  for (int o = id0; o < 128; o += stride){
    float acc = b_a[o];
    for (int c = 0; c < 128; ++c) acc += W_a[o*128 + c] * b_d2[c];
    ball[o] = acc;
  }
}

// ---------------- A: h = W_in x + b_in ; LN1 -> hn --------------------------
__global__ __launch_bounds__(256) void k_a(const float* __restrict__ x,
    const unsigned short* __restrict__ WINF, const float* __restrict__ b_in,
    const float* __restrict__ g1, const float* __restrict__ be1,
    float* __restrict__ H, unsigned short* __restrict__ HN){
  __shared__ unsigned short xT[64][72];  // 64 pts x 64 c (bf16), row 144B
  int tid = threadIdx.x;
  int bb = blockIdx.x >> 6;
  int n0 = (blockIdx.x & 63) * 64;
  for (int i = tid; i < 4096; i += 256){
    int c = i >> 6, nn = i & 63;
    xT[nn][c] = f2bf(x[((size_t)(bb*64 + c))*4096 + n0 + nn]);
  }
  __syncthreads();
  int lane = tid & 63, w = tid >> 6, m16 = lane & 15, g = lane >> 4;
  const char* xb = (const char*)&xT[0][0];
  s8 a0 = *(const s8*)(xb + (w*16 + m16)*144 + 16*g);
  s8 a1 = *(const s8*)(xb + (w*16 + m16)*144 + 64 + 16*g);
  const f4 zf = {0.f, 0.f, 0.f, 0.f};
  f4 acc[8];
  #pragma unroll
  for (int t = 0; t < 8; ++t) acc[t] = zf;
  #pragma unroll
  for (int t = 0; t < 8; ++t){
    s8 b0 = *(const s8*)(WINF + ((size_t)(t*2 + 0)*64 + lane)*8);
    s8 b1 = *(const s8*)(WINF + ((size_t)(t*2 + 1)*64 + lane)*8);
    acc[t] = MFMA16(a0, b0, acc[t]);
    acc[t] = MFMA16(a1, b1, acc[t]);
  }
  float mean[4], rstd[4];
  #pragma unroll
  for (int r = 0; r < 4; ++r){
    float ls = 0.f, lq = 0.f;
    #pragma unroll
    for (int t = 0; t < 8; ++t){
      float v = acc[t][r] + b_in[t*16 + m16];
      ls += v; lq += v*v;
    }
    ls += __shfl_xor(ls, 1); ls += __shfl_xor(ls, 2); ls += __shfl_xor(ls, 4); ls += __shfl_xor(ls, 8);
    lq += __shfl_xor(lq, 1); lq += __shfl_xor(lq, 2); lq += __shfl_xor(lq, 4); lq += __shfl_xor(lq, 8);
    float mn = ls * (1.f/128.f);
    float vr = lq * (1.f/128.f) - mn*mn;
    mean[r] = mn;
    rstd[r] = rsqrtf(vr + 1e-5f);
  }
  int ptbase = blockIdx.x*64 + w*16;
  #pragma unroll
  for (int t = 0; t < 8; ++t){
    int o = t*16 + m16;
    float bi = b_in[o], gg = g1[o], be = be1[o];
    #pragma unroll
    for (int r = 0; r < 4; ++r){
      int pt = ptbase + 4*g + r;
      float v = acc[t][r] + bi;
      H[(size_t)pt*128 + o] = v;
      HN[(size_t)pt*128 + o] = f2bf((v - mean[r])*rstd[r]*gg + be);
    }
  }
}

// ---------------- generic data(A) x table(B) GEMM, K=128 -------------------
// MODE 0: qkv output (no bias, kv-interleaved row of 384) ; MODE 1: F1 (bias+relu, 512 cols)
template<int MODE>
__global__ __launch_bounds__(256) void k_gemm(const unsigned short* __restrict__ A,
    const unsigned short* __restrict__ Btab, const float* __restrict__ bias,
    unsigned short* __restrict__ out){
  int lane = threadIdx.x & 63, w = threadIdx.x >> 6;
  int m0 = blockIdx.x*64 + w*16;
  int by = blockIdx.y;
  int m16 = lane & 15, g = lane >> 4;
  const f4 zf = {0.f, 0.f, 0.f, 0.f};
  f4 acc[8];
  #pragma unroll
  for (int t = 0; t < 8; ++t) acc[t] = zf;
  #pragma unroll
  for (int s = 0; s < 4; ++s){
    s8 af = *(const s8*)(A + ((size_t)(m0 + m16))*128 + s*32 + g*8);
    #pragma unroll
    for (int t = 0; t < 8; ++t){
      s8 bf = *(const s8*)(Btab + ((size_t)((by*8 + t)*4 + s)*64 + lane)*8);
      acc[t] = MFMA16(af, bf, acc[t]);
    }
  }
  #pragma unroll
  for (int t = 0; t < 8; ++t){
    int col = by*128 + t*16 + m16;
    #pragma unroll
    for (int r = 0; r < 4; ++r){
      int pt = m0 + 4*g + r;
      float v = acc[t][r];
      if (MODE == 0){
        int pos = (col < 128) ? 2*col : ((col < 256) ? 2*(col - 128) + 1 : col);
        out[(size_t)pt*384 + pos] = f2bf(v);
      } else {
        v = fmaxf(v + bias[col], 0.f);
        out[(size_t)pt*512 + col] = f2bf(v);
      }
    }
  }
}

// ---------------- F2: out(B,C,N) += W_f2 @ z^T + b_f2 ----------------------
__global__ __launch_bounds__(256) void k_f2(const unsigned short* __restrict__ wf2f,
    const unsigned short* __restrict__ Z, const float* __restrict__ b_f2,
    float* __restrict__ out){
  int lane = threadIdx.x & 63, w = threadIdx.x >> 6;
  int mt = blockIdx.x*4 + w;       // o-tile 0..7
  int p0 = blockIdx.y*128;         // point base
  int m16 = lane & 15, g = lane >> 4;
  const f4 zf = {0.f, 0.f, 0.f, 0.f};
  f4 acc[8];
  #pragma unroll
  for (int t = 0; t < 8; ++t) acc[t] = zf;
  #pragma unroll 4
  for (int s = 0; s < 16; ++s){
    s8 af = *(const s8*)(wf2f + ((size_t)(mt*16 + s)*64 + lane)*8);
    #pragma unroll
    for (int t = 0; t < 8; ++t){
      s8 bf = *(const s8*)(Z + (size_t)(p0 + t*16 + m16)*512 + s*32 + g*8);
      acc[t] = MFMA16(af, bf, acc[t]);
    }
  }
  #pragma unroll
  for (int t = 0; t < 8; ++t){
    #pragma unroll
    for (int r = 0; r < 4; ++r){
      int o = mt*16 + 4*g + r;
      int pt = p0 + t*16 + m16;
      int b = pt >> 12, n = pt & 4095;
      size_t ix = (((size_t)(b*128 + o)) << 12) | (unsigned)n;
      out[ix] += acc[t][r] + b_f2[o];
    }
  }
}

// ---------------- KNN: exact top-16, f32 prefilter + f64 exact key ---------
__global__ __launch_bounds__(256) void k_knn(const float4* __restrict__ PP,
    int* __restrict__ IDXo){
  __shared__ float4 pp_s[4096];                      // 64KB
  __shared__ unsigned long long batch_sh[256][17];   // 34.8KB, +1 pad for banks
  int tid = threadIdx.x;
  int b = blockIdx.x >> 5, tile = blockIdx.x & 31;
  for (int i = tid; i < 4096; i += 256) pp_s[i] = PP[b*4096 + i];
  __syncthreads();
  int qn = tile*128 + (tid & 127);
  int half = tid >> 7;
  int lane = tid & 63;
  float4 me = pp_s[qn];
  double mx = (double)me.x, my = (double)me.y, mz = (double)me.z;
  unsigned long long top[16];
  #pragma unroll
  for (int j = 0; j < 16; ++j) top[j] = ~0ull;
  unsigned long long thr = ~0ull;
  float thrf = __builtin_inff();
  int cnt = 0;
  unsigned long long* br = batch_sh[tid];
  int base = half*2048;
  #pragma unroll 1
  for (int ii = 0; ii < 512; ++ii){
    #pragma unroll
    for (int u = 0; u < 4; ++u){
      int i = ii*4 + u;
      int m = base + ((i + lane*33) & 2047);
      float4 cd = pp_s[m];
      float dx = me.x - cd.x, dy = me.y - cd.y, dz = me.z - cd.z;
      float d2f = dx*dx + dy*dy + dz*dz;
      if (m != qn && d2f < thrf){
        // exact: fp32 diffs are exact in f64; products exact; <=1ulp on the sum
        double ddx = mx - (double)cd.x;
        double ddy = my - (double)cd.y;
        double ddz = mz - (double)cd.z;
        double d2 = ddx*ddx + ddy*ddy + ddz*ddz;
        unsigned long long key =
            (__builtin_bit_cast(unsigned long long, d2) & ~0xFFFull) | (unsigned)m;
        if (key < thr){ br[cnt] = key; ++cnt; }
      }
    }
    if (__any(cnt >= 12)){ drain16(br, cnt, top, thr); thrf = thr2f(thr); }
  }
  drain16(br, cnt, top, thr);
  #pragma unroll
  for (int j = 0; j < 16; ++j) br[j] = top[j];
  __syncthreads();
  if (tid < 128){
    unsigned long long other[16];
    #pragma unroll
    for (int j = 0; j < 16; ++j) other[j] = batch_sh[tid + 128][j];
    merge16(top, other);
    int* op = IDXo + ((size_t)(b*4096 + qn))*16;
    #pragma unroll
    for (int j = 0; j < 16; ++j) op[j] = (int)(unsigned)(top[j] & 0xFFFull);
  }
}

// ---------------- ATTN: per-point fused kNN attention ----------------------
__global__ __launch_bounds__(256) void k_attn(const float* __restrict__ pcoord,
    const int* __restrict__ IDX, const unsigned short* __restrict__ QKV,
    const unsigned short* __restrict__ W1F, const unsigned short* __restrict__ WD2F,
    const unsigned short* __restrict__ WDAF, const float* __restrict__ b_d2,
    const float* __restrict__ BALL, unsigned short* __restrict__ Y){
  __shared__ unsigned short kv_sh[4][4][16][64];  // [wave][pt][m][32 kv-pairs] 32KB
  __shared__ unsigned short t1_sh[4][2048];       // [wave][16m x 128c] swizzled 16KB
  __shared__ int idx_sh[4][4][16];                // 1KB
  int tid = threadIdx.x;
  int w = tid >> 6, lane = tid & 63;
  int m16 = lane & 15, g = lane >> 4;
  int P0 = blockIdx.x*16 + w*4;
  const f4 zf = {0.f, 0.f, 0.f, 0.f};
  if (lane < 16){
    #pragma unroll
    for (int q = 0; q < 4; ++q) idx_sh[w][q][lane] = IDX[(size_t)(P0 + q)*16 + lane];
  }
  // ---- build per-point A-frags: relu(rel_aug @ W1aug^T) in bf16 ----
  s8 a[4][4];
  #pragma unroll
  for (int q = 0; q < 4; ++q){
    int pt = P0 + q;
    int bq = pt >> 12, nn = pt & 4095;
    const float* pb = pcoord + (size_t)bq*3*4096;
    s8 arel = {0,0,0,0,0,0,0,0};
    if (lane < 16){
      int jn = idx_sh[w][q][m16];
      float rx = pb[nn] - pb[jn];
      float ry = pb[4096 + nn] - pb[4096 + jn];
      float rz = pb[8192 + nn] - pb[8192 + jn];
      arel[0] = (short)f2bf(rx); arel[1] = (short)f2bf(ry);
      arel[2] = (short)f2bf(rz); arel[3] = (short)0x3F80; // 1.0 bf16
    }
    f4 t1a[8];
    #pragma unroll
    for (int t = 0; t < 8; ++t){
      s8 bw = *(const s8*)(W1F + ((size_t)t*64 + lane)*8);
      t1a[t] = MFMA16(arel, bw, zf);
    }
    #pragma unroll
    for (int t = 0; t < 8; ++t){
      int c = t*16 + m16;
      #pragma unroll
      for (int r = 0; r < 4; ++r){
        int m = 4*g + r;
        int byt = (m*256 + c*2) ^ ((m & 7) << 4);
        t1_sh[w][byt >> 1] = f2bf(fmaxf(t1a[t][r], 0.f));
      }
    }
    const char* t1b = (const char*)&t1_sh[w][0];
    #pragma unroll
    for (int s = 0; s < 4; ++s){
      int byt = (m16*256 + 64*s + 16*g) ^ ((m16 & 7) << 4);
      a[q][s] = *(const s8*)(t1b + byt);
    }
  }
  // ---- main: 4 passes over o-quarters ----
  #pragma unroll 1
  for (int pass = 0; pass < 4; ++pass){
    uint4 gk[4][2];
    #pragma unroll
    for (int q = 0; q < 4; ++q){
      int pt = P0 + q, bq = pt >> 12;
      #pragma unroll
      for (int i2 = 0; i2 < 2; ++i2){
        int mm = i2*8 + (lane >> 3);
        int jn = idx_sh[w][q][mm];
        gk[q][i2] = *(const uint4*)((const char*)QKV
            + ((size_t)(bq*4096 + jn))*768 + pass*128 + (lane & 7)*16);
      }
    }
    #pragma unroll
    for (int q = 0; q < 4; ++q){
      #pragma unroll
      for (int i2 = 0; i2 < 2; ++i2)
        *(uint4*)((char*)&kv_sh[w][q][i2*8][0] + lane*16) = gk[q][i2];
    }
    #pragma unroll
    for (int tl = 0; tl < 2; ++tl){
      int tg = pass*2 + tl;
      f4 dacc[4], lacc[4];
      #pragma unroll
      for (int q = 0; q < 4; ++q){ dacc[q] = zf; lacc[q] = zf; }
      #pragma unroll
      for (int s = 0; s < 4; ++s){
        s8 wd2 = *(const s8*)(WD2F + ((size_t)(tg*4 + s)*64 + lane)*8);
        s8 wda = *(const s8*)(WDAF + ((size_t)(tg*4 + s)*64 + lane)*8);
        #pragma unroll
        for (int q = 0; q < 4; ++q){
          dacc[q] = MFMA16(a[q][s], wd2, dacc[q]);
          lacc[q] = MFMA16(a[q][s], wda, lacc[q]);
        }
      }
      int col = tg*16 + m16;
      float bd2c = b_d2[col];
      float ballc = BALL[col];
      #pragma unroll
      for (int q = 0; q < 4; ++q){
        int pt = P0 + q;
        float qac = bf2f(QKV[(size_t)pt*384 + 256 + col]);
        float lg[4], dd[4], vv[4];
        #pragma unroll
        for (int r = 0; r < 4; ++r){
          int m = 4*g + r;
          unsigned kvp = *(const unsigned*)&kv_sh[w][q][m][(tl*16 + m16)*2];
          float ka = bf2f((unsigned short)(kvp & 0xFFFFu));
          vv[r] = bf2f((unsigned short)(kvp >> 16));
          lg[r] = lacc[q][r] + qac - ka + ballc;
          dd[r] = dacc[q][r] + bd2c;
        }
        float mx = fmaxf(fmaxf(lg[0], lg[1]), fmaxf(lg[2], lg[3]));
        mx = fmaxf(mx, __shfl_xor(mx, 16));
        mx = fmaxf(mx, __shfl_xor(mx, 32));
        float e0 = __expf(lg[0] - mx), e1 = __expf(lg[1] - mx);
        float e2 = __expf(lg[2] - mx), e3 = __expf(lg[3] - mx);
        float ss = e0 + e1 + e2 + e3;
        ss += __shfl_xor(ss, 16); ss += __shfl_xor(ss, 32);
        float inv = 1.f / ss;
        float yp = e0*(vv[0] + dd[0]) + e1*(vv[1] + dd[1])
                 + e2*(vv[2] + dd[2]) + e3*(vv[3] + dd[3]);
        yp *= inv;
        yp += __shfl_xor(yp, 16); yp += __shfl_xor(yp, 32);
        if (lane < 16) Y[(size_t)pt*128 + col] = f2bf(yp);
      }
    }
  }
}

// ---------------- D1: h2 = h + y ; d_out = h2 ; hn2 = LN2(h2) ---------------
__global__ __launch_bounds__(64) void k_d1(const float* __restrict__ H,
    const unsigned short* __restrict__ Y, const float* __restrict__ g2,
    const float* __restrict__ be2, float* __restrict__ outp,
    unsigned short* __restrict__ HN2){
  int pt = blockIdx.x*64 + threadIdx.x;
  int b = pt >> 12, n = pt & 4095;
  const float4* h4 = (const float4*)(H + (size_t)pt*128);
  const uint4* y4 = (const uint4*)((const char*)Y + (size_t)pt*256);
  float h2[128];
  float ls = 0.f, lq = 0.f;
  #pragma unroll
  for (int i = 0; i < 16; ++i){
    float4 ha = h4[2*i], hb = h4[2*i + 1];
    uint4 yv = y4[i];
    float v0 = ha.x + bf2f((unsigned short)(yv.x & 0xFFFFu));
    float v1 = ha.y + bf2f((unsigned short)(yv.x >> 16));
    float v2 = ha.z + bf2f((unsigned short)(yv.y & 0xFFFFu));
    float v3 = ha.w + bf2f((unsigned short)(yv.y >> 16));
    float v4 = hb.x + bf2f((unsigned short)(yv.z & 0xFFFFu));
    float v5 = hb.y + bf2f((unsigned short)(yv.z >> 16));
    float v6 = hb.z + bf2f((unsigned short)(yv.w & 0xFFFFu));
    float v7 = hb.w + bf2f((unsigned short)(yv.w >> 16));
    h2[8*i+0] = v0; h2[8*i+1] = v1; h2[8*i+2] = v2; h2[8*i+3] = v3;
    h2[8*i+4] = v4; h2[8*i+5] = v5; h2[8*i+6] = v6; h2[8*i+7] = v7;
    ls += v0+v1+v2+v3+v4+v5+v6+v7;
    lq += v0*v0+v1*v1+v2*v2+v3*v3+v4*v4+v5*v5+v6*v6+v7*v7;
  }
  float mn = ls * (1.f/128.f);
  float vr = lq * (1.f/128.f) - mn*mn;
  float rs = rsqrtf(vr + 1e-5f);
  #pragma unroll
  for (int c = 0; c < 128; ++c)
    outp[(((size_t)(b*128 + c)) << 12) | (unsigned)n] = h2[c];
  #pragma unroll
  for (int i = 0; i < 16; ++i){
    unsigned uu[4];
    #pragma unroll
    for (int k = 0; k < 4; ++k){
      int c0 = 8*i + 2*k, c1 = c0 + 1;
      unsigned lo = f2bf((h2[c0] - mn)*rs*g2[c0] + be2[c0]);
      unsigned hi = f2bf((h2[c1] - mn)*rs*g2[c1] + be2[c1]);
      uu[k] = lo | (hi << 16);
    }
    *(uint4*)((char*)HN2 + (size_t)pt*256 + i*16) = make_uint4(uu[0], uu[1], uu[2], uu[3]);
  }
}

// ---------------------------------------------------------------------------
extern "C" void kernel_launch(void* const* d_in, const int* in_sizes, int n_in,
                              void* d_out, int out_size, void* d_ws, size_t ws_size,
                              hipStream_t stream){
  const float* x    = (const float*)d_in[0];
  const float* p    = (const float*)d_in[1];
  const float* W_in = (const float*)d_in[2];
  const float* b_in = (const float*)d_in[3];
  const float* W_q  = (const float*)d_in[4];
  const float* W_k  = (const float*)d_in[5];
  const float* W_v  = (const float*)d_in[6];
  const float* W_d1 = (const float*)d_in[7];
  const float* b_d1 = (const float*)d_in[8];
  const float* W_d2 = (const float*)d_in[9];
  const float* b_d2 = (const float*)d_in[10];
  const float* W_a  = (const float*)d_in[11];
  const float* b_a  = (const float*)d_in[12];
  const float* g1   = (const float*)d_in[13];
  const float* be1  = (const float*)d_in[14];
  const float* g2   = (const float*)d_in[15];
  const float* be2  = (const float*)d_in[16];
  const float* W_f1 = (const float*)d_in[17];
  const float* b_f1 = (const float*)d_in[18];
  const float* W_f2 = (const float*)d_in[19];
  const float* b_f2 = (const float*)d_in[20];
  float* out = (float*)d_out;
  char* ws = (char*)d_ws;

  float*          H    = (float*)(ws + 0);
  unsigned short* HN   = (unsigned short*)(ws + 16777216);
  unsigned short* QKV  = (unsigned short*)(ws + 25165824);
  unsigned short* Z    = (unsigned short*)(ws + 16777216);  // alias HN+QKV
  unsigned short* Y    = (unsigned short*)(ws + 50331648);
  unsigned short* HN2  = (unsigned short*)(ws + 58720256);
  int*            IDX  = (int*)(ws + 67108864);
  float4*         PP   = (float4*)(ws + 69206016);
  char* tab = ws + 69730304;
  unsigned short* WCATF = (unsigned short*)(tab + 0);
  unsigned short* WF1F  = (unsigned short*)(tab + 98304);
  unsigned short* WF2F  = (unsigned short*)(tab + 229376);
  unsigned short* WD2F  = (unsigned short*)(tab + 360448);
  unsigned short* WDAF  = (unsigned short*)(tab + 393216);
  unsigned short* W1F   = (unsigned short*)(tab + 425984);
  unsigned short* WINF  = (unsigned short*)(tab + 434176);
  float*          BALL  = (float*)(tab + 450560);
  float*          TK    = (float*)(tab + 451072);
  float*          TQ    = (float*)(tab + 516608);
  float*          TD    = (float*)(tab + 582144);

  k_p1<<<dim3(384), dim3(128), 0, stream>>>(W_a, W_k, W_q, W_d2, TK, TQ, TD);
  k_pack<<<dim3(256), dim3(256), 0, stream>>>(p, W_v, W_d1, b_d1, W_in, W_f1, W_f2,
      W_a, b_a, b_d2, W_d2, TK, TQ, TD,
      PP, WCATF, WF1F, WF2F, WD2F, WDAF, W1F, WINF, BALL);
  k_knn<<<dim3(256), dim3(256), 0, stream>>>(PP, IDX);
  k_a<<<dim3(512), dim3(256), 0, stream>>>(x, WINF, b_in, g1, be1, H, HN);
  k_gemm<0><<<dim3(512, 3), dim3(256), 0, stream>>>(HN, WCATF, nullptr, QKV);
  k_attn<<<dim3(2048), dim3(256), 0, stream>>>(p, IDX, QKV, W1F, WD2F, WDAF, b_d2, BALL, Y);
  k_d1<<<dim3(512), dim3(64), 0, stream>>>(H, Y, g2, be2, out, HN2);
  k_gemm<1><<<dim3(512, 4), dim3(256), 0, stream>>>(HN2, WF1F, b_f1, Z);
  k_f2<<<dim3(2, 256), dim3(256), 0, stream>>>(WF2F, Z, b_f2, out);
}

// Round 3
// 470.359 us; speedup vs baseline: 1.2612x; 1.2612x over previous
//
#include <hip/hip_runtime.h>
#include <stdint.h>

// ---------------------------------------------------------------------------
// PTBlock fused implementation (B=8, Cin=64, C=128, N=4096, k=16, HID=512)
// Pipeline: P1(weight products) -> P2(pack frag tables + pp) -> A(h=Win x + LN1 -> hn)
//   -> GEMM qkv (hn @ [Wak|Wv|Waq]^T, kv interleaved) -> KNN -> ATTN -> D1(h+y, LN2)
//   -> F1 (FFN up, relu) -> F2 (FFN down + residual add into d_out)
// R3 change: k_knn restructured for occupancy:
//   - candidates streamed from global (L2-resident 64KB/batch, broadcast addrs)
//   - 8 threads per query x 512 candidates, bitonic merge tree across subsets
//   - LDS = 34.8KB drain buffer only -> 4 blocks/CU, 16 waves/CU
// ---------------------------------------------------------------------------

typedef __attribute__((ext_vector_type(8))) short s8;
typedef __attribute__((ext_vector_type(4))) float f4;

#define MFMA16(a,b,c) __builtin_amdgcn_mfma_f32_16x16x32_bf16(a,b,c,0,0,0)

__device__ __forceinline__ float bf2f(unsigned short u){
  unsigned x = ((unsigned)u) << 16; return __builtin_bit_cast(float, x);
}
__device__ __forceinline__ unsigned short f2bf(float f){
  unsigned x = __builtin_bit_cast(unsigned, f);
  x = x + 0x7FFFu + ((x >> 16) & 1u);
  return (unsigned short)(x >> 16);
}

// ---------------- sorting-network helpers (u64 keys) -----------------------
__device__ __forceinline__ void ce64(unsigned long long &a, unsigned long long &b){
  unsigned long long x = a, y = b;
  bool c = x < y;
  a = c ? x : y;
  b = c ? y : x;
}
// Batcher odd-even mergesort, n=16 (63 CE)
__device__ __forceinline__ void sort16(unsigned long long v[16]){
  #pragma unroll
  for (int p = 1; p < 16; p <<= 1){
    #pragma unroll
    for (int k = p; k >= 1; k >>= 1){
      #pragma unroll
      for (int j = k % p; j + k < 16; j += 2*k){
        #pragma unroll
        for (int i = 0; i < k; ++i){
          if (i + j + k < 16){
            if (((i+j) / (2*p)) == ((i+j+k) / (2*p))) ce64(v[i+j], v[i+j+k]);
          }
        }
      }
    }
  }
}
// sort a bitonic 16-sequence ascending
__device__ __forceinline__ void bitonic16(unsigned long long v[16]){
  #pragma unroll
  for (int k = 8; k >= 1; k >>= 1){
    #pragma unroll
    for (int i = 0; i < 16; ++i){
      if ((i & k) == 0) ce64(v[i], v[i | k]);
    }
  }
}
// top (asc) x w (asc) -> top = sorted 16 smallest of the 32
__device__ __forceinline__ void merge16(unsigned long long top[16], const unsigned long long w[16]){
  unsigned long long t[16];
  #pragma unroll
  for (int i = 0; i < 16; ++i){
    unsigned long long a = top[i], b = w[15 - i];
    t[i] = a < b ? a : b;
  }
  bitonic16(t);
  #pragma unroll
  for (int i = 0; i < 16; ++i) top[i] = t[i];
}
__device__ __forceinline__ void drain16(unsigned long long* br, int &cnt,
                                        unsigned long long top[16], unsigned long long &thr){
  unsigned long long v[16];
  #pragma unroll
  for (int j = 0; j < 16; ++j){
    unsigned long long t = br[j];
    v[j] = (j < cnt) ? t : ~0ull;
  }
  cnt = 0;
  sort16(v);
  merge16(top, v);
  thr = top[15];
}
// loose f32 upper bound for the d2 encoded in thr (for the fp32 pre-filter)
__device__ __forceinline__ float thr2f(unsigned long long thr){
  if (thr == ~0ull) return __builtin_inff();
  double dt = __builtin_bit_cast(double, (unsigned long long)(thr | 0xFFFull));
  float f = (float)dt;
  return f + fmaxf(f * 2e-6f, 2e-7f);
}

// ---------------- P1: Wak = Wa@Wk, Waq = Wa@Wq, Wda = Wa@Wd2 ---------------
__global__ __launch_bounds__(128) void k_p1(const float* __restrict__ W_a,
    const float* __restrict__ W_k, const float* __restrict__ W_q, const float* __restrict__ W_d2,
    float* __restrict__ tk, float* __restrict__ tq, float* __restrict__ td){
  int which = blockIdx.x >> 7, row = blockIdx.x & 127, c = threadIdx.x;
  const float* X = (which == 0) ? W_k : ((which == 1) ? W_q : W_d2);
  float* O = (which == 0) ? tk : ((which == 1) ? tq : td);
  float acc = 0.f;
  #pragma unroll 8
  for (int i = 0; i < 128; ++i) acc += W_a[row*128 + i] * X[i*128 + c];
  O[row*128 + c] = acc;
}

// ---------------- P2: pack fragment tables, pp, ball -----------------------
// frag index: entry(((tg*S + s)*64 + l)*8 + j) = M[16*tg + (l&15)][32*s + 8*(l>>4) + j]
__global__ __launch_bounds__(256) void k_pack(
    const float* __restrict__ p, const float* __restrict__ W_v,
    const float* __restrict__ W_d1, const float* __restrict__ b_d1,
    const float* __restrict__ W_in, const float* __restrict__ W_f1, const float* __restrict__ W_f2,
    const float* __restrict__ W_a, const float* __restrict__ b_a, const float* __restrict__ b_d2,
    const float* __restrict__ W_d2,
    const float* __restrict__ tk, const float* __restrict__ tq, const float* __restrict__ td,
    float4* __restrict__ pp, unsigned short* __restrict__ wcatf, unsigned short* __restrict__ wf1f,
    unsigned short* __restrict__ wf2f, unsigned short* __restrict__ wd2f,
    unsigned short* __restrict__ wdaf, unsigned short* __restrict__ w1f,
    unsigned short* __restrict__ winf, float* __restrict__ ball){
  int id0 = blockIdx.x * blockDim.x + threadIdx.x;
  int stride = gridDim.x * blockDim.x;
  // pp[b][m] = (px,py,pz,|p|^2)
  for (int i = id0; i < 32768; i += stride){
    int b = i >> 12, m = i & 4095;
    float xx = p[(b*3 + 0)*4096 + m];
    float yy = p[(b*3 + 1)*4096 + m];
    float zz = p[(b*3 + 2)*4096 + m];
    pp[i] = float4{xx, yy, zz, xx*xx + yy*yy + zz*zz};
  }
  // Wcatf: rows 0-127 Wak, 128-255 W_v, 256-383 Waq ; K=128 (S=4)
  for (int i = id0; i < 49152; i += stride){
    int tg = i >> 11, s = (i >> 9) & 3, l = (i >> 3) & 63, j = i & 7;
    int row = tg*16 + (l & 15), k = s*32 + (l >> 4)*8 + j;
    float v;
    if (row < 128) v = tk[row*128 + k];
    else if (row < 256) v = W_v[(row - 128)*128 + k];
    else v = tq[(row - 256)*128 + k];
    wcatf[i] = f2bf(v);
  }
  // Wf1f: 512 rows, K=128 (S=4)
  for (int i = id0; i < 65536; i += stride){
    int tg = i >> 11, s = (i >> 9) & 3, l = (i >> 3) & 63, j = i & 7;
    int row = tg*16 + (l & 15), k = s*32 + (l >> 4)*8 + j;
    wf1f[i] = f2bf(W_f1[row*128 + k]);
  }
  // Wf2f: 128 rows, K=512 (S=16)  (used as A-table in F2)
  for (int i = id0; i < 65536; i += stride){
    int mt = i >> 13, s = (i >> 9) & 15, l = (i >> 3) & 63, j = i & 7;
    int row = mt*16 + (l & 15), k = s*32 + (l >> 4)*8 + j;
    wf2f[i] = f2bf(W_f2[row*512 + k]);
  }
  // Wd2f: 128 rows K=128
  for (int i = id0; i < 16384; i += stride){
    int tg = i >> 11, s = (i >> 9) & 3, l = (i >> 3) & 63, j = i & 7;
    int row = tg*16 + (l & 15), k = s*32 + (l >> 4)*8 + j;
    wd2f[i] = f2bf(W_d2[row*128 + k]);
  }
  // Wdaf from Wda=Wa@Wd2
  for (int i = id0; i < 16384; i += stride){
    int tg = i >> 11, s = (i >> 9) & 3, l = (i >> 3) & 63, j = i & 7;
    int row = tg*16 + (l & 15), k = s*32 + (l >> 4)*8 + j;
    wdaf[i] = f2bf(td[row*128 + k]);
  }
  // W1f: B-frag of W1aug (rows=c, K=4 padded into one 32-step)
  for (int i = id0; i < 4096; i += stride){
    int tg = i >> 9, l = (i >> 3) & 63, j = i & 7;
    int c = tg*16 + (l & 15);
    float v = 0.f;
    if (l < 16 && j < 4) v = (j < 3) ? W_d1[c*3 + j] : b_d1[c];
    w1f[i] = f2bf(v);
  }
  // Winf: 128 rows K=64 (S=2)
  for (int i = id0; i < 8192; i += stride){
    int tg = i >> 10, s = (i >> 9) & 1, l = (i >> 3) & 63, j = i & 7;
    int row = tg*16 + (l & 15), k = s*32 + (l >> 4)*8 + j;
    winf[i] = f2bf(W_in[row*64 + k]);
  }
  // ball[o] = b_a[o] + sum_c W_a[o][c]*b_d2[c]
  for (int o = id0; o < 128; o += stride){
    float acc = b_a[o];
    for (int c = 0; c < 128; ++c) acc += W_a[o*128 + c] * b_d2[c];
    ball[o] = acc;
  }
}

// ---------------- A: h = W_in x + b_in ; LN1 -> hn --------------------------
__global__ __launch_bounds__(256) void k_a(const float* __restrict__ x,
    const unsigned short* __restrict__ WINF, const float* __restrict__ b_in,
    const float* __restrict__ g1, const float* __restrict__ be1,
    float* __restrict__ H, unsigned short* __restrict__ HN){
  __shared__ unsigned short xT[64][72];  // 64 pts x 64 c (bf16), row 144B
  int tid = threadIdx.x;
  int bb = blockIdx.x >> 6;
  int n0 = (blockIdx.x & 63) * 64;
  for (int i = tid; i < 4096; i += 256){
    int c = i >> 6, nn = i & 63;
    xT[nn][c] = f2bf(x[((size_t)(bb*64 + c))*4096 + n0 + nn]);
  }
  __syncthreads();
  int lane = tid & 63, w = tid >> 6, m16 = lane & 15, g = lane >> 4;
  const char* xb = (const char*)&xT[0][0];
  s8 a0 = *(const s8*)(xb + (w*16 + m16)*144 + 16*g);
  s8 a1 = *(const s8*)(xb + (w*16 + m16)*144 + 64 + 16*g);
  const f4 zf = {0.f, 0.f, 0.f, 0.f};
  f4 acc[8];
  #pragma unroll
  for (int t = 0; t < 8; ++t) acc[t] = zf;
  #pragma unroll
  for (int t = 0; t < 8; ++t){
    s8 b0 = *(const s8*)(WINF + ((size_t)(t*2 + 0)*64 + lane)*8);
    s8 b1 = *(const s8*)(WINF + ((size_t)(t*2 + 1)*64 + lane)*8);
    acc[t] = MFMA16(a0, b0, acc[t]);
    acc[t] = MFMA16(a1, b1, acc[t]);
  }
  float mean[4], rstd[4];
  #pragma unroll
  for (int r = 0; r < 4; ++r){
    float ls = 0.f, lq = 0.f;
    #pragma unroll
    for (int t = 0; t < 8; ++t){
      float v = acc[t][r] + b_in[t*16 + m16];
      ls += v; lq += v*v;
    }
    ls += __shfl_xor(ls, 1); ls += __shfl_xor(ls, 2); ls += __shfl_xor(ls, 4); ls += __shfl_xor(ls, 8);
    lq += __shfl_xor(lq, 1); lq += __shfl_xor(lq, 2); lq += __shfl_xor(lq, 4); lq += __shfl_xor(lq, 8);
    float mn = ls * (1.f/128.f);
    float vr = lq * (1.f/128.f) - mn*mn;
    mean[r] = mn;
    rstd[r] = rsqrtf(vr + 1e-5f);
  }
  int ptbase = blockIdx.x*64 + w*16;
  #pragma unroll
  for (int t = 0; t < 8; ++t){
    int o = t*16 + m16;
    float bi = b_in[o], gg = g1[o], be = be1[o];
    #pragma unroll
    for (int r = 0; r < 4; ++r){
      int pt = ptbase + 4*g + r;
      float v = acc[t][r] + bi;
      H[(size_t)pt*128 + o] = v;
      HN[(size_t)pt*128 + o] = f2bf((v - mean[r])*rstd[r]*gg + be);
    }
  }
}

// ---------------- generic data(A) x table(B) GEMM, K=128 -------------------
// MODE 0: qkv output (no bias, kv-interleaved row of 384) ; MODE 1: F1 (bias+relu, 512 cols)
template<int MODE>
__global__ __launch_bounds__(256) void k_gemm(const unsigned short* __restrict__ A,
    const unsigned short* __restrict__ Btab, const float* __restrict__ bias,
    unsigned short* __restrict__ out){
  int lane = threadIdx.x & 63, w = threadIdx.x >> 6;
  int m0 = blockIdx.x*64 + w*16;
  int by = blockIdx.y;
  int m16 = lane & 15, g = lane >> 4;
  const f4 zf = {0.f, 0.f, 0.f, 0.f};
  f4 acc[8];
  #pragma unroll
  for (int t = 0; t < 8; ++t) acc[t] = zf;
  #pragma unroll
  for (int s = 0; s < 4; ++s){
    s8 af = *(const s8*)(A + ((size_t)(m0 + m16))*128 + s*32 + g*8);
    #pragma unroll
    for (int t = 0; t < 8; ++t){
      s8 bf = *(const s8*)(Btab + ((size_t)((by*8 + t)*4 + s)*64 + lane)*8);
      acc[t] = MFMA16(af, bf, acc[t]);
    }
  }
  #pragma unroll
  for (int t = 0; t < 8; ++t){
    int col = by*128 + t*16 + m16;
    #pragma unroll
    for (int r = 0; r < 4; ++r){
      int pt = m0 + 4*g + r;
      float v = acc[t][r];
      if (MODE == 0){
        int pos = (col < 128) ? 2*col : ((col < 256) ? 2*(col - 128) + 1 : col);
        out[(size_t)pt*384 + pos] = f2bf(v);
      } else {
        v = fmaxf(v + bias[col], 0.f);
        out[(size_t)pt*512 + col] = f2bf(v);
      }
    }
  }
}

// ---------------- F2: out(B,C,N) += W_f2 @ z^T + b_f2 ----------------------
__global__ __launch_bounds__(256) void k_f2(const unsigned short* __restrict__ wf2f,
    const unsigned short* __restrict__ Z, const float* __restrict__ b_f2,
    float* __restrict__ out){
  int lane = threadIdx.x & 63, w = threadIdx.x >> 6;
  int mt = blockIdx.x*4 + w;       // o-tile 0..7
  int p0 = blockIdx.y*128;         // point base
  int m16 = lane & 15, g = lane >> 4;
  const f4 zf = {0.f, 0.f, 0.f, 0.f};
  f4 acc[8];
  #pragma unroll
  for (int t = 0; t < 8; ++t) acc[t] = zf;
  #pragma unroll 4
  for (int s = 0; s < 16; ++s){
    s8 af = *(const s8*)(wf2f + ((size_t)(mt*16 + s)*64 + lane)*8);
    #pragma unroll
    for (int t = 0; t < 8; ++t){
      s8 bf = *(const s8*)(Z + (size_t)(p0 + t*16 + m16)*512 + s*32 + g*8);
      acc[t] = MFMA16(af, bf, acc[t]);
    }
  }
  #pragma unroll
  for (int t = 0; t < 8; ++t){
    #pragma unroll
    for (int r = 0; r < 4; ++r){
      int o = mt*16 + 4*g + r;
      int pt = p0 + t*16 + m16;
      int b = pt >> 12, n = pt & 4095;
      size_t ix = (((size_t)(b*128 + o)) << 12) | (unsigned)n;
      out[ix] += acc[t][r] + b_f2[o];
    }
  }
}

// ---------------- KNN: exact top-16, 8 threads/query, L2-streamed ----------
// grid: 1024 blocks = 8 batches x 128 tiles (32 queries each)
// thread (q = tid&31, sub = tid>>5): scans candidates [sub*512, sub*512+512)
// LDS: only the 34.8KB drain/merge buffer -> 4 blocks/CU, 16 waves/CU
__global__ __launch_bounds__(256, 4) void k_knn(const float4* __restrict__ PP,
    int* __restrict__ IDXo){
  __shared__ unsigned long long batch_sh[256][17];   // 34.8KB
  int tid = threadIdx.x;
  int b = blockIdx.x >> 7;
  int tile = blockIdx.x & 127;
  int q = tid & 31;
  int sub = tid >> 5;
  int qn = tile*32 + q;
  const float4* pb = PP + (size_t)b*4096;
  float4 me = pb[qn];
  double mx = (double)me.x, my = (double)me.y, mz = (double)me.z;
  unsigned long long top[16];
  #pragma unroll
  for (int j = 0; j < 16; ++j) top[j] = ~0ull;
  unsigned long long thr = ~0ull;
  float thrf = __builtin_inff();
  int cnt = 0;
  unsigned long long* br = batch_sh[tid];
  int base = sub << 9;
  #pragma unroll 1
  for (int ii = 0; ii < 128; ++ii){
    #pragma unroll
    for (int u = 0; u < 4; ++u){
      int m = base + ii*4 + u;
      float4 cd = pb[m];
      float dx = me.x - cd.x, dy = me.y - cd.y, dz = me.z - cd.z;
      float d2f = dx*dx + dy*dy + dz*dz;
      if (m != qn && d2f < thrf){
        // exact: fp32 diffs are exact in f64; products exact; <=1ulp on the sum
        double ddx = mx - (double)cd.x;
        double ddy = my - (double)cd.y;
        double ddz = mz - (double)cd.z;
        double d2 = ddx*ddx + ddy*ddy + ddz*ddz;
        unsigned long long key =
            (__builtin_bit_cast(unsigned long long, d2) & ~0xFFFull) | (unsigned)m;
        if (key < thr){ br[cnt] = key; ++cnt; }
      }
    }
    if (__any(cnt >= 12)){ drain16(br, cnt, top, thr); thrf = thr2f(thr); }
  }
  drain16(br, cnt, top, thr);
  // merge tree across the 8 subsets (batch_sh rows double as publish slots)
  #pragma unroll
  for (int step = 4; step >= 1; step >>= 1){
    __syncthreads();
    if (sub < 2*step){
      #pragma unroll
      for (int j = 0; j < 16; ++j) batch_sh[tid][j] = top[j];
    }
    __syncthreads();
    if (sub < step){
      unsigned long long other[16];
      #pragma unroll
      for (int j = 0; j < 16; ++j) other[j] = batch_sh[(sub + step)*32 + q][j];
      merge16(top, other);
    }
  }
  if (sub == 0){
    int* op = IDXo + ((size_t)(b*4096 + qn))*16;
    #pragma unroll
    for (int j = 0; j < 16; ++j) op[j] = (int)(unsigned)(top[j] & 0xFFFull);
  }
}

// ---------------- ATTN: per-point fused kNN attention ----------------------
__global__ __launch_bounds__(256) void k_attn(const float* __restrict__ pcoord,
    const int* __restrict__ IDX, const unsigned short* __restrict__ QKV,
    const unsigned short* __restrict__ W1F, const unsigned short* __restrict__ WD2F,
    const unsigned short* __restrict__ WDAF, const float* __restrict__ b_d2,
    const float* __restrict__ BALL, unsigned short* __restrict__ Y){
  __shared__ unsigned short kv_sh[4][4][16][64];  // [wave][pt][m][32 kv-pairs] 32KB
  __shared__ unsigned short t1_sh[4][2048];       // [wave][16m x 128c] swizzled 16KB
  __shared__ int idx_sh[4][4][16];                // 1KB
  int tid = threadIdx.x;
  int w = tid >> 6, lane = tid & 63;
  int m16 = lane & 15, g = lane >> 4;
  int P0 = blockIdx.x*16 + w*4;
  const f4 zf = {0.f, 0.f, 0.f, 0.f};
  if (lane < 16){
    #pragma unroll
    for (int q = 0; q < 4; ++q) idx_sh[w][q][lane] = IDX[(size_t)(P0 + q)*16 + lane];
  }
  // ---- build per-point A-frags: relu(rel_aug @ W1aug^T) in bf16 ----
  s8 a[4][4];
  #pragma unroll
  for (int q = 0; q < 4; ++q){
    int pt = P0 + q;
    int bq = pt >> 12, nn = pt & 4095;
    const float* pb = pcoord + (size_t)bq*3*4096;
    s8 arel = {0,0,0,0,0,0,0,0};
    if (lane < 16){
      int jn = idx_sh[w][q][m16];
      float rx = pb[nn] - pb[jn];
      float ry = pb[4096 + nn] - pb[4096 + jn];
      float rz = pb[8192 + nn] - pb[8192 + jn];
      arel[0] = (short)f2bf(rx); arel[1] = (short)f2bf(ry);
      arel[2] = (short)f2bf(rz); arel[3] = (short)0x3F80; // 1.0 bf16
    }
    f4 t1a[8];
    #pragma unroll
    for (int t = 0; t < 8; ++t){
      s8 bw = *(const s8*)(W1F + ((size_t)t*64 + lane)*8);
      t1a[t] = MFMA16(arel, bw, zf);
    }
    #pragma unroll
    for (int t = 0; t < 8; ++t){
      int c = t*16 + m16;
      #pragma unroll
      for (int r = 0; r < 4; ++r){
        int m = 4*g + r;
        int byt = (m*256 + c*2) ^ ((m & 7) << 4);
        t1_sh[w][byt >> 1] = f2bf(fmaxf(t1a[t][r], 0.f));
      }
    }
    const char* t1b = (const char*)&t1_sh[w][0];
    #pragma unroll
    for (int s = 0; s < 4; ++s){
      int byt = (m16*256 + 64*s + 16*g) ^ ((m16 & 7) << 4);
      a[q][s] = *(const s8*)(t1b + byt);
    }
  }
  // ---- main: 4 passes over o-quarters ----
  #pragma unroll 1
  for (int pass = 0; pass < 4; ++pass){
    uint4 gk[4][2];
    #pragma unroll
    for (int q = 0; q < 4; ++q){
      int pt = P0 + q, bq = pt >> 12;
      #pragma unroll
      for (int i2 = 0; i2 < 2; ++i2){
        int mm = i2*8 + (lane >> 3);
        int jn = idx_sh[w][q][mm];
        gk[q][i2] = *(const uint4*)((const char*)QKV
            + ((size_t)(bq*4096 + jn))*768 + pass*128 + (lane & 7)*16);
      }
    }
    #pragma unroll
    for (int q = 0; q < 4; ++q){
      #pragma unroll
      for (int i2 = 0; i2 < 2; ++i2)
        *(uint4*)((char*)&kv_sh[w][q][i2*8][0] + lane*16) = gk[q][i2];
    }
    #pragma unroll
    for (int tl = 0; tl < 2; ++tl){
      int tg = pass*2 + tl;
      f4 dacc[4], lacc[4];
      #pragma unroll
      for (int q = 0; q < 4; ++q){ dacc[q] = zf; lacc[q] = zf; }
      #pragma unroll
      for (int s = 0; s < 4; ++s){
        s8 wd2 = *(const s8*)(WD2F + ((size_t)(tg*4 + s)*64 + lane)*8);
        s8 wda = *(const s8*)(WDAF + ((size_t)(tg*4 + s)*64 + lane)*8);
        #pragma unroll
        for (int q = 0; q < 4; ++q){
          dacc[q] = MFMA16(a[q][s], wd2, dacc[q]);
          lacc[q] = MFMA16(a[q][s], wda, lacc[q]);
        }
      }
      int col = tg*16 + m16;
      float bd2c = b_d2[col];
      float ballc = BALL[col];
      #pragma unroll
      for (int q = 0; q < 4; ++q){
        int pt = P0 + q;
        float qac = bf2f(QKV[(size_t)pt*384 + 256 + col]);
        float lg[4], dd[4], vv[4];
        #pragma unroll
        for (int r = 0; r < 4; ++r){
          int m = 4*g + r;
          unsigned kvp = *(const unsigned*)&kv_sh[w][q][m][(tl*16 + m16)*2];
          float ka = bf2f((unsigned short)(kvp & 0xFFFFu));
          vv[r] = bf2f((unsigned short)(kvp >> 16));
          lg[r] = lacc[q][r] + qac - ka + ballc;
          dd[r] = dacc[q][r] + bd2c;
        }
        float mx = fmaxf(fmaxf(lg[0], lg[1]), fmaxf(lg[2], lg[3]));
        mx = fmaxf(mx, __shfl_xor(mx, 16));
        mx = fmaxf(mx, __shfl_xor(mx, 32));
        float e0 = __expf(lg[0] - mx), e1 = __expf(lg[1] - mx);
        float e2 = __expf(lg[2] - mx), e3 = __expf(lg[3] - mx);
        float ss = e0 + e1 + e2 + e3;
        ss += __shfl_xor(ss, 16); ss += __shfl_xor(ss, 32);
        float inv = 1.f / ss;
        float yp = e0*(vv[0] + dd[0]) + e1*(vv[1] + dd[1])
                 + e2*(vv[2] + dd[2]) + e3*(vv[3] + dd[3]);
        yp *= inv;
        yp += __shfl_xor(yp, 16); yp += __shfl_xor(yp, 32);
        if (lane < 16) Y[(size_t)pt*128 + col] = f2bf(yp);
      }
    }
  }
}

// ---------------- D1: h2 = h + y ; d_out = h2 ; hn2 = LN2(h2) ---------------
__global__ __launch_bounds__(64) void k_d1(const float* __restrict__ H,
    const unsigned short* __restrict__ Y, const float* __restrict__ g2,
    const float* __restrict__ be2, float* __restrict__ outp,
    unsigned short* __restrict__ HN2){
  int pt = blockIdx.x*64 + threadIdx.x;
  int b = pt >> 12, n = pt & 4095;
  const float4* h4 = (const float4*)(H + (size_t)pt*128);
  const uint4* y4 = (const uint4*)((const char*)Y + (size_t)pt*256);
  float h2[128];
  float ls = 0.f, lq = 0.f;
  #pragma unroll
  for (int i = 0; i < 16; ++i){
    float4 ha = h4[2*i], hb = h4[2*i + 1];
    uint4 yv = y4[i];
    float v0 = ha.x + bf2f((unsigned short)(yv.x & 0xFFFFu));
    float v1 = ha.y + bf2f((unsigned short)(yv.x >> 16));
    float v2 = ha.z + bf2f((unsigned short)(yv.y & 0xFFFFu));
    float v3 = ha.w + bf2f((unsigned short)(yv.y >> 16));
    float v4 = hb.x + bf2f((unsigned short)(yv.z & 0xFFFFu));
    float v5 = hb.y + bf2f((unsigned short)(yv.z >> 16));
    float v6 = hb.z + bf2f((unsigned short)(yv.w & 0xFFFFu));
    float v7 = hb.w + bf2f((unsigned short)(yv.w >> 16));
    h2[8*i+0] = v0; h2[8*i+1] = v1; h2[8*i+2] = v2; h2[8*i+3] = v3;
    h2[8*i+4] = v4; h2[8*i+5] = v5; h2[8*i+6] = v6; h2[8*i+7] = v7;
    ls += v0+v1+v2+v3+v4+v5+v6+v7;
    lq += v0*v0+v1*v1+v2*v2+v3*v3+v4*v4+v5*v5+v6*v6+v7*v7;
  }
  float mn = ls * (1.f/128.f);
  float vr = lq * (1.f/128.f) - mn*mn;
  float rs = rsqrtf(vr + 1e-5f);
  #pragma unroll
  for (int c = 0; c < 128; ++c)
    outp[(((size_t)(b*128 + c)) << 12) | (unsigned)n] = h2[c];
  #pragma unroll
  for (int i = 0; i < 16; ++i){
    unsigned uu[4];
    #pragma unroll
    for (int k = 0; k < 4; ++k){
      int c0 = 8*i + 2*k, c1 = c0 + 1;
      unsigned lo = f2bf((h2[c0] - mn)*rs*g2[c0] + be2[c0]);
      unsigned hi = f2bf((h2[c1] - mn)*rs*g2[c1] + be2[c1]);
      uu[k] = lo | (hi << 16);
    }
    *(uint4*)((char*)HN2 + (size_t)pt*256 + i*16) = make_uint4(uu[0], uu[1], uu[2], uu[3]);
  }
}

// ---------------------------------------------------------------------------
extern "C" void kernel_launch(void* const* d_in, const int* in_sizes, int n_in,
                              void* d_out, int out_size, void* d_ws, size_t ws_size,
                              hipStream_t stream){
  const float* x    = (const float*)d_in[0];
  const float* p    = (const float*)d_in[1];
  const float* W_in = (const float*)d_in[2];
  const float* b_in = (const float*)d_in[3];
  const float* W_q  = (const float*)d_in[4];
  const float* W_k  = (const float*)d_in[5];
  const float* W_v  = (const float*)d_in[6];
  const float* W_d1 = (const float*)d_in[7];
  const float* b_d1 = (const float*)d_in[8];
  const float* W_d2 = (const float*)d_in[9];
  const float* b_d2 = (const float*)d_in[10];
  const float* W_a  = (const float*)d_in[11];
  const float* b_a  = (const float*)d_in[12];
  const float* g1   = (const float*)d_in[13];
  const float* be1  = (const float*)d_in[14];
  const float* g2   = (const float*)d_in[15];
  const float* be2  = (const float*)d_in[16];
  const float* W_f1 = (const float*)d_in[17];
  const float* b_f1 = (const float*)d_in[18];
  const float* W_f2 = (const float*)d_in[19];
  const float* b_f2 = (const float*)d_in[20];
  float* out = (float*)d_out;
  char* ws = (char*)d_ws;

  float*          H    = (float*)(ws + 0);
  unsigned short* HN   = (unsigned short*)(ws + 16777216);
  unsigned short* QKV  = (unsigned short*)(ws + 25165824);
  unsigned short* Z    = (unsigned short*)(ws + 16777216);  // alias HN+QKV
  unsigned short* Y    = (unsigned short*)(ws + 50331648);
  unsigned short* HN2  = (unsigned short*)(ws + 58720256);
  int*            IDX  = (int*)(ws + 67108864);
  float4*         PP   = (float4*)(ws + 69206016);
  char* tab = ws + 69730304;
  unsigned short* WCATF = (unsigned short*)(tab + 0);
  unsigned short* WF1F  = (unsigned short*)(tab + 98304);
  unsigned short* WF2F  = (unsigned short*)(tab + 229376);
  unsigned short* WD2F  = (unsigned short*)(tab + 360448);
  unsigned short* WDAF  = (unsigned short*)(tab + 393216);
  unsigned short* W1F   = (unsigned short*)(tab + 425984);
  unsigned short* WINF  = (unsigned short*)(tab + 434176);
  float*          BALL  = (float*)(tab + 450560);
  float*          TK    = (float*)(tab + 451072);
  float*          TQ    = (float*)(tab + 516608);
  float*          TD    = (float*)(tab + 582144);

  k_p1<<<dim3(384), dim3(128), 0, stream>>>(W_a, W_k, W_q, W_d2, TK, TQ, TD);
  k_pack<<<dim3(256), dim3(256), 0, stream>>>(p, W_v, W_d1, b_d1, W_in, W_f1, W_f2,
      W_a, b_a, b_d2, W_d2, TK, TQ, TD,
      PP, WCATF, WF1F, WF2F, WD2F, WDAF, W1F, WINF, BALL);
  k_knn<<<dim3(1024), dim3(256), 0, stream>>>(PP, IDX);
  k_a<<<dim3(512), dim3(256), 0, stream>>>(x, WINF, b_in, g1, be1, H, HN);
  k_gemm<0><<<dim3(512, 3), dim3(256), 0, stream>>>(HN, WCATF, nullptr, QKV);
  k_attn<<<dim3(2048), dim3(256), 0, stream>>>(p, IDX, QKV, W1F, WD2F, WDAF, b_d2, BALL, Y);
  k_d1<<<dim3(512), dim3(64), 0, stream>>>(H, Y, g2, be2, out, HN2);
  k_gemm<1><<<dim3(512, 4), dim3(256), 0, stream>>>(HN2, WF1F, b_f1, Z);
  k_f2<<<dim3(2, 256), dim3(256), 0, stream>>>(WF2F, Z, b_f2, out);
}